// Round 14
// baseline (124.178 us; speedup 1.0000x reference)
//
#include <hip/hip_runtime.h>
#include <hip/hip_bf16.h>

typedef __bf16 bf16x8 __attribute__((ext_vector_type(8)));
typedef float f32x4 __attribute__((ext_vector_type(4)));

// Pre-kernel: clusters (128x512 f32) -> bf16 in ws, plus fp32 c2[128].
__global__ __launch_bounds__(64)
void prep_clusters(const float* __restrict__ c, __bf16* __restrict__ cb,
                   float* __restrict__ c2)
{
    const int row = blockIdx.x;     // 0..127
    const int l = threadIdx.x;      // 0..63
    const float* p = c + row * 512 + l * 8;
    f32x4 u0 = *(const f32x4*)p;
    f32x4 u1 = *(const f32x4*)(p + 4);
    bf16x8 v;
    float s = 0.f;
#pragma unroll
    for (int j = 0; j < 4; ++j) {
        v[j]     = (__bf16)u0[j];
        v[4 + j] = (__bf16)u1[j];
        s += u0[j] * u0[j] + u1[j] * u1[j];
    }
    *(bf16x8*)(cb + row * 512 + l * 8) = v;
#pragma unroll
    for (int off = 32; off >= 1; off >>= 1) s += __shfl_xor(s, off);
    if (l == 0) c2[row] = s;
}

// OCCUPANCY x2 (the one untested-post-write-fix lever): 512-thread blocks,
// 8 waves each owning 16 cols -> bR[16]=64 VGPR (was 128), total ~115 VGPR,
// __launch_bounds__(512,4) -> 4 waves/SIMD (16 waves/CU, 2 blocks/CU).
// Doubled wave-stream interleaving fills the ~68% per-block read-idle gap
// measured in the pass-duty arithmetic (32 KB delivered in ~3200cyc of a
// ~9900cyc pass). All R11 wins retained: reg-staged linear reads, XOR
// swizzle, qt-bounce FULL-LINE NT stores (qt now block-wide so two 16-col
// waves' halves merge into complete 128B lines), counted vmcnt.
__global__ __launch_bounds__(512, 4)
void cluster_q_mfma(const float* __restrict__ x,
                    const __bf16* __restrict__ cb,
                    const float* __restrict__ c2,
                    float* __restrict__ out)
{
    __shared__ float lds[16 * 512];      // one 32 KB x-tile (16 rows x 512)
    __shared__ float rsx[8][16];         // per-wave partial row sums
    __shared__ float qt[16][132];        // block-wide q bounce (padded rows)

    const int tid = threadIdx.x;        // 0..511
    const int l = tid & 63;
    const int w = tid >> 6;             // wave 0..7: owns cols w*16..w*16+15
    const int m = l & 15;               // fragment row (A) / col (B)
    const int g = l >> 4;               // k-group 0..3
    const long brow = (long)blockIdx.x * 256;

    const float c2v = c2[w * 16 + m];

    // Persistent B: col w*16+m, all 512 k. 16 x b128 loads, 64 VGPRs.
    bf16x8 bR[16];
#pragma unroll
    for (int ks = 0; ks < 16; ++ks)
        bR[ks] = *(const bf16x8*)(cb + (w * 16 + m) * 512 + ks * 32 + g * 8);

    // Staging: 512 threads, G[4]; instr i_ covers rows i_*4 + (tid>>7);
    // lane chunk = tid&127 (each instr = one fully-linear 8 KB row-quad).
    const int t7 = tid >> 7;
    const int ck = tid & 127;

    // LDS read bases (bytes): row m, chunk (ks*8 + (2g|2g+1)^(m&7)).
    const int rbo0 = m * 2048 + (((2 * g)     ^ (m & 7)) * 16);
    const int rbo1 = m * 2048 + (((2 * g + 1) ^ (m & 7)) * 16);

    f32x4 G[4];

#define SB __builtin_amdgcn_sched_barrier(0)
#define GLOAD(P)                                                          \
    { _Pragma("unroll")                                                   \
      for (int i_ = 0; i_ < 4; ++i_)                                      \
          G[i_] = *(const f32x4*)(x + (brow + (long)(P) * 16              \
                     + i_ * 4 + t7) * 512 + ck * 4); }
#define DSWRITE()                                                         \
    { _Pragma("unroll")                                                   \
      for (int i_ = 0; i_ < 4; ++i_) {                                    \
          const int row_l = i_ * 4 + t7;                                  \
          const int swc = (ck & ~7) | ((ck & 7) ^ (row_l & 7));           \
          *(f32x4*)(&lds[row_l * 512 + swc * 4]) = G[i_];                 \
      } }

    // Prologue: tile 0 through registers into LDS; tile-1 loads in flight.
    GLOAD(0);
    asm volatile("s_waitcnt vmcnt(0)" ::: "memory");
    DSWRITE();
    GLOAD(1);
    asm volatile("s_waitcnt lgkmcnt(0)" ::: "memory");
    __builtin_amdgcn_s_barrier();

#pragma unroll 1
    for (int p = 0; p < 16; ++p) {
        // P1: compute pass p. One MFMA per ks (wave's single col-fragment).
        f32x4 acc = f32x4{0.f, 0.f, 0.f, 0.f};
        float x2p = 0.f;
        const char* L = (const char*)&lds[0];
#pragma unroll
        for (int ks = 0; ks < 16; ++ks) {
            f32x4 u0 = *(const f32x4*)(L + rbo0 + ks * 128);
            f32x4 u1 = *(const f32x4*)(L + rbo1 + ks * 128);
            bf16x8 aF;
#pragma unroll
            for (int j = 0; j < 4; ++j) {
                aF[j]     = (__bf16)u0[j];
                aF[4 + j] = (__bf16)u1[j];
                x2p += u0[j] * u0[j] + u1[j] * u1[j];
            }
            acc = __builtin_amdgcn_mfma_f32_16x16x32_bf16(aF, bR[ks], acc, 0, 0, 0);
        }

        // P2: q values + per-wave partial row sums.
        x2p += __shfl_xor(x2p, 16);
        x2p += __shfl_xor(x2p, 32);
        float x2r[4], rs[4];
#pragma unroll
        for (int r = 0; r < 4; ++r) {
            x2r[r] = __shfl(x2p, g * 4 + r);
            rs[r] = 0.f;
        }
#pragma unroll
        for (int r = 0; r < 4; ++r) {
            float d2 = fmaxf(x2r[r] + c2v - 2.f * acc[r], 0.f);
            float qv = __builtin_amdgcn_rcpf(1.f + d2);   // ALPHA=1
            acc[r] = qv;
            rs[r] += qv;
        }
#pragma unroll
        for (int r = 0; r < 4; ++r) {
            rs[r] += __shfl_xor(rs[r], 1);
            rs[r] += __shfl_xor(rs[r], 2);
            rs[r] += __shfl_xor(rs[r], 4);
            rs[r] += __shfl_xor(rs[r], 8);
        }
        if (m == 0) {
#pragma unroll
            for (int r = 0; r < 4; ++r) rsx[w][g * 4 + r] = rs[r];
        }

        // BARRIER-1: tile-p reads done (single buffer WAR) + rsx published.
        asm volatile("s_waitcnt lgkmcnt(0)" ::: "memory");
        __builtin_amdgcn_s_barrier();
        SB;

        // P3: staging. Outstanding = 4 loads(p+1) [oldest] + 1 NT store(p-1)
        // [newest] -> vmcnt(1) drains exactly the loads (p=0: no store yet).
        if (p < 15) {
            if (p == 0) { asm volatile("s_waitcnt vmcnt(0)" ::: "memory"); }
            else        { asm volatile("s_waitcnt vmcnt(1)" ::: "memory"); }
            SB;
            DSWRITE();
            if (p < 14) { GLOAD(p + 2); }
        }

        // P4: normalize into block-wide qt.
        float inv[4];
#pragma unroll
        for (int r = 0; r < 4; ++r) {
            const int row16 = g * 4 + r;
            float s = rsx[0][row16] + rsx[1][row16] + rsx[2][row16] +
                      rsx[3][row16] + rsx[4][row16] + rsx[5][row16] +
                      rsx[6][row16] + rsx[7][row16];
            inv[r] = __builtin_amdgcn_rcpf(s);
        }
#pragma unroll
        for (int r = 0; r < 4; ++r)
            qt[g * 4 + r][w * 16 + m] = acc[r] * inv[r];

        // BARRIER-2: qt complete (all waves) + tile p+1 in LDS.
        asm volatile("s_waitcnt lgkmcnt(0)" ::: "memory");
        __builtin_amdgcn_s_barrier();
        SB;

        // P5: full-line readback + NT store. 512 threads cover 16 rows x
        // 128 cols; each wave-instr writes 1 KB contiguous (8 full lines).
        {
            const int row = tid >> 5;        // 0..15
            const int cc = tid & 31;         // 16B chunk in the 512B row
            f32x4 v = *(const f32x4*)&qt[row][cc * 4];
            __builtin_nontemporal_store(
                v, (f32x4*)(out + (brow + p * 16 + row) * 128 + cc * 4));
        }
        SB;
    }
#undef GLOAD
#undef DSWRITE
#undef SB
}

extern "C" void kernel_launch(void* const* d_in, const int* in_sizes, int n_in,
                              void* d_out, int out_size, void* d_ws, size_t ws_size,
                              hipStream_t stream)
{
    const float* x = (const float*)d_in[0];
    const float* c = (const float*)d_in[1];
    float* out = (float*)d_out;

    float*  c2ws = (float*)d_ws;                        // 128 floats
    __bf16* cbws = (__bf16*)((char*)d_ws + 1024);       // 128x512 bf16 = 128 KB

    hipLaunchKernelGGL(prep_clusters, dim3(128), dim3(64), 0, stream, c, cbws, c2ws);

    const int N = in_sizes[0] / 512;                    // 131072 rows
    dim3 grid(N / 256), block(512);                     // 512 blocks = 2/CU
    hipLaunchKernelGGL(cluster_q_mfma, grid, block, 0, stream, x, cbws, c2ws, out);
}

// Round 16
// 80.374 us; speedup vs baseline: 1.5450x; 1.5450x over previous
//
#include <hip/hip_runtime.h>
#include <hip/hip_bf16.h>

typedef __bf16 bf16x8 __attribute__((ext_vector_type(8)));
typedef float f32x4 __attribute__((ext_vector_type(4)));

// Pre-kernel: clusters (128x512 f32) -> bf16 in ws, plus fp32 c2[128].
__global__ __launch_bounds__(64)
void prep_clusters(const float* __restrict__ c, __bf16* __restrict__ cb,
                   float* __restrict__ c2)
{
    const int row = blockIdx.x;     // 0..127
    const int l = threadIdx.x;      // 0..63
    const float* p = c + row * 512 + l * 8;
    f32x4 u0 = *(const f32x4*)p;
    f32x4 u1 = *(const f32x4*)(p + 4);
    bf16x8 v;
    float s = 0.f;
#pragma unroll
    for (int j = 0; j < 4; ++j) {
        v[j]     = (__bf16)u0[j];
        v[4 + j] = (__bf16)u1[j];
        s += u0[j] * u0[j] + u1[j] * u1[j];
    }
    *(bf16x8*)(cb + row * 512 + l * 8) = v;
#pragma unroll
    for (int off = 32; off >= 1; off >>= 1) s += __shfl_xor(s, off);
    if (l == 0) c2[row] = s;
}

__device__ __forceinline__ void gl_lds16(const float* g, float* l)
{
    __builtin_amdgcn_global_load_lds(
        (const __attribute__((address_space(1))) void*)g,
        (__attribute__((address_space(3))) void*)l, 16, 0, 0);
}

// CLEAN OCCUPANCY x2 TEST (16 waves/CU vs R11's 8), engineered around the
// three prior failures: (a) bR[16]=64 VGPR (16 cols/wave) + gl_lds staging
// (zero staging registers) -> ~110 VGPR, real headroom under the 128 cap of
// __launch_bounds__(512,4) [R14's spill]; (b) LDS double buffer -> stage
// issues at pass top with full-pass latency overlap [R9/R8's depth problem,
// solved without registers]; (c) EVERY barrier preceded by memory-clobbering
// waitcnt asm -> compiler cannot hoist LDS ops across barriers [R15's race].
// Retained R11 wins: both-sides XOR swizzle, full-line NT stores via qt
// bounce (block-wide: two 16-col wave pieces merge into complete 128B lines).
__global__ __launch_bounds__(512, 4)
void cluster_q_mfma(const float* __restrict__ x,
                    const __bf16* __restrict__ cb,
                    const float* __restrict__ c2,
                    float* __restrict__ out)
{
    __shared__ float lds[2][16 * 512];   // 2 x 32 KB x-tiles
    __shared__ float rsx[8][16];         // per-wave partial row sums
    __shared__ float qt[16][132];        // block-wide q bounce (8.25 KB)

    const int tid = threadIdx.x;        // 0..511
    const int l = tid & 63;
    const int w = tid >> 6;             // wave 0..7: owns cols w*16..w*16+15
    const int m = l & 15;               // fragment row (A) / col (B)
    const int g = l >> 4;               // k-group 0..3
    const long brow = (long)blockIdx.x * 256;

    const float c2v = c2[w * 16 + m];

    // Persistent B: col w*16+m, all 512 k. 16 x b128 loads = 64 VGPRs.
    bf16x8 bR[16];
#pragma unroll
    for (int ks = 0; ks < 16; ++ks)
        bR[ks] = *(const bf16x8*)(cb + (w * 16 + m) * 512 + ks * 32 + g * 8);

    // Staging: wave w stages rows {2w, 2w+1} of the 16-row tile; instr i_
    // covers row 2w+(i_>>1), half i_&1 (1 KB contiguous). Source chunk is
    // pre-swizzled within its 128B group (gl_lds writes linearly).
    int co[2];
#pragma unroll
    for (int q = 0; q < 2; ++q)
        co[q] = (l & 56) | ((l & 7) ^ ((2 * w + q) & 7));

    // LDS read bases (bytes): row m, chunk (ks*8 + (2g|2g+1)^(m&7)).
    const int rbo0 = m * 2048 + (((2 * g)     ^ (m & 7)) * 16);
    const int rbo1 = m * 2048 + (((2 * g + 1) ^ (m & 7)) * 16);

#define SB __builtin_amdgcn_sched_barrier(0)
#define STAGE(BUF, P)                                                     \
    { _Pragma("unroll")                                                   \
      for (int i_ = 0; i_ < 4; ++i_)                                      \
          gl_lds16(x + (brow + (long)(P) * 16 + 2 * w + (i_ >> 1)) * 512  \
                     + (i_ & 1) * 256 + co[i_ >> 1] * 4,                  \
                   &lds[BUF][(2 * w + (i_ >> 1)) * 512 + (i_ & 1) * 256]); }

    // Prologue: tile 0 into buf0.
    STAGE(0, 0);
    asm volatile("s_waitcnt vmcnt(0)" ::: "memory");
    __builtin_amdgcn_s_barrier();

#pragma unroll 1
    for (int p = 0; p < 16; ++p) {
        const int cur = p & 1;

        // P1: stage tile p+1 into the other buffer (full-pass overlap; no
        // WAR hazard: buf cur^1 reads were certified at BARRIER-1(p-1)).
        if (p < 15) { STAGE(cur ^ 1, p + 1); }
        SB;

        // P2: compute pass p from lds[cur]. All 8 waves read the same rows.
        f32x4 acc = f32x4{0.f, 0.f, 0.f, 0.f};
        float x2p = 0.f;
        const char* L = (const char*)&lds[cur][0];
#pragma unroll
        for (int ks = 0; ks < 16; ++ks) {
            f32x4 u0 = *(const f32x4*)(L + rbo0 + ks * 128);
            f32x4 u1 = *(const f32x4*)(L + rbo1 + ks * 128);
            bf16x8 aF;
#pragma unroll
            for (int j = 0; j < 4; ++j) {
                aF[j]     = (__bf16)u0[j];
                aF[4 + j] = (__bf16)u1[j];
                x2p += u0[j] * u0[j] + u1[j] * u1[j];
            }
            acc = __builtin_amdgcn_mfma_f32_16x16x32_bf16(aF, bR[ks], acc, 0, 0, 0);
        }

        // P3: q + per-wave partial row sums (over this wave's 16 cols).
        x2p += __shfl_xor(x2p, 16);
        x2p += __shfl_xor(x2p, 32);
        float x2r[4], rs[4];
#pragma unroll
        for (int r = 0; r < 4; ++r) {
            x2r[r] = __shfl(x2p, g * 4 + r);
            rs[r] = 0.f;
        }
#pragma unroll
        for (int r = 0; r < 4; ++r) {
            float d2 = fmaxf(x2r[r] + c2v - 2.f * acc[r], 0.f);
            float qv = __builtin_amdgcn_rcpf(1.f + d2);   // ALPHA=1
            acc[r] = qv;
            rs[r] = qv;
        }
#pragma unroll
        for (int r = 0; r < 4; ++r) {
            rs[r] += __shfl_xor(rs[r], 1);
            rs[r] += __shfl_xor(rs[r], 2);
            rs[r] += __shfl_xor(rs[r], 4);
            rs[r] += __shfl_xor(rs[r], 8);
        }
        if (m == 0) {
#pragma unroll
            for (int r = 0; r < 4; ++r) rsx[w][g * 4 + r] = rs[r];
        }
        // BARRIER-1: tile-p reads done by all waves + rsx published.
        asm volatile("s_waitcnt lgkmcnt(0)" ::: "memory");
        __builtin_amdgcn_s_barrier();
        SB;

        // P4: normalize into block-wide qt; certify tile p+1 (vmcnt) and qt
        // (lgkm) at BARRIER-2. vmcnt(0) is ~free: stage was issued a full
        // compute phase ago; only an old NT store also drains.
        float inv[4];
#pragma unroll
        for (int r = 0; r < 4; ++r) {
            const int row16 = g * 4 + r;
            float s = rsx[0][row16] + rsx[1][row16] + rsx[2][row16] +
                      rsx[3][row16] + rsx[4][row16] + rsx[5][row16] +
                      rsx[6][row16] + rsx[7][row16];
            inv[r] = __builtin_amdgcn_rcpf(s);
        }
#pragma unroll
        for (int r = 0; r < 4; ++r)
            qt[g * 4 + r][w * 16 + m] = acc[r] * inv[r];

        asm volatile("s_waitcnt vmcnt(0) lgkmcnt(0)" ::: "memory");
        __builtin_amdgcn_s_barrier();   // BARRIER-2: qt + tile p+1 visible
        SB;

        // P5: full-line readback + NT store. Each half-wave covers one row
        // (512 B contiguous); wave instr = 1 KB = 8 complete 128B lines.
        {
            const int row = tid >> 5;        // 0..15
            const int cc = tid & 31;         // 16B chunk within the row
            f32x4 v = *(const f32x4*)&qt[row][cc * 4];
            __builtin_nontemporal_store(
                v, (f32x4*)(out + (brow + p * 16 + row) * 128 + cc * 4));
        }
        SB;
    }
#undef STAGE
#undef SB
}

extern "C" void kernel_launch(void* const* d_in, const int* in_sizes, int n_in,
                              void* d_out, int out_size, void* d_ws, size_t ws_size,
                              hipStream_t stream)
{
    const float* x = (const float*)d_in[0];
    const float* c = (const float*)d_in[1];
    float* out = (float*)d_out;

    float*  c2ws = (float*)d_ws;                        // 128 floats
    __bf16* cbws = (__bf16*)((char*)d_ws + 1024);       // 128x512 bf16 = 128 KB

    hipLaunchKernelGGL(prep_clusters, dim3(128), dim3(64), 0, stream, c, cbws, c2ws);

    const int N = in_sizes[0] / 512;                    // 131072 rows
    dim3 grid(N / 256), block(512);                     // 512 blocks = 2/CU
    hipLaunchKernelGGL(cluster_q_mfma, grid, block, 0, stream, x, cbws, c2ws, out);
}

// Round 17
// 66.483 us; speedup vs baseline: 1.8678x; 1.2089x over previous
//
#include <hip/hip_runtime.h>
#include <hip/hip_bf16.h>

typedef __bf16 bf16x8 __attribute__((ext_vector_type(8)));
typedef float f32x4 __attribute__((ext_vector_type(4)));

// Pre-kernel: clusters (128x512 f32) -> bf16 in ws, plus fp32 c2[128].
__global__ __launch_bounds__(64)
void prep_clusters(const float* __restrict__ c, __bf16* __restrict__ cb,
                   float* __restrict__ c2)
{
    const int row = blockIdx.x;     // 0..127
    const int l = threadIdx.x;      // 0..63
    const float* p = c + row * 512 + l * 8;
    f32x4 u0 = *(const f32x4*)p;
    f32x4 u1 = *(const f32x4*)(p + 4);
    bf16x8 v;
    float s = 0.f;
#pragma unroll
    for (int j = 0; j < 4; ++j) {
        v[j]     = (__bf16)u0[j];
        v[4 + j] = (__bf16)u1[j];
        s += u0[j] * u0[j] + u1[j] * u1[j];
    }
    *(bf16x8*)(cb + row * 512 + l * 8) = v;
#pragma unroll
    for (int off = 32; off >= 1; off >>= 1) s += __shfl_xor(s, off);
    if (l == 0) c2[row] = s;
}

// R11 RESTORED (best: 65.9 us = 4.86 TB/s = 99.4% of the m146 4.89 TB/s
// compute-stream reference). Structure: 512 blocks x 4 waves (2 blocks/CU),
// persistent B in registers (128 VGPR), reg-staged fully-linear x reads
// (plain global_load_dwordx4 -> G[8] -> XOR-swizzled single LDS tile),
// counted vmcnt(2), 2 barriers/pass, qt-bounce FULL-LINE nontemporal stores
// (the round-11 win: WRITE_SIZE 595->64 MB). Axes closed by experiment:
// issue order/depth (R12/R13 neutral, R9 regress), barriers (R13), occupancy
// (R14/R16 regress), gl_lds path (R3-R7, R16: always slower).
__global__ __launch_bounds__(256, 2)
void cluster_q_mfma(const float* __restrict__ x,
                    const __bf16* __restrict__ cb,
                    const float* __restrict__ c2,
                    float* __restrict__ out)
{
    __shared__ float lds[16 * 512];      // one 32 KB tile (16 rows x 512)
    __shared__ float rsx[4][16];         // per-wave partial row sums
    __shared__ float qt[4][16 * 32];     // per-wave q transpose tile (2 KB)

    const int tid = threadIdx.x;
    const int l = tid & 63;
    const int w = tid >> 6;         // wave 0..3: owns cols w*32 .. w*32+31
    const int m = l & 15;           // fragment row (A) / col (B)
    const int g = l >> 4;           // k-group 0..3
    const long brow = (long)blockIdx.x * 256;

    float c2v[2];
#pragma unroll
    for (int nb = 0; nb < 2; ++nb) c2v[nb] = c2[w * 32 + nb * 16 + m];

    // Persistent B: cols w*32+nb*16+m, all 512 k. 32 x b128 loads, 128 VGPRs.
    bf16x8 bR[2][16];
#pragma unroll
    for (int nb = 0; nb < 2; ++nb)
#pragma unroll
        for (int ks = 0; ks < 16; ++ks)
            bR[nb][ks] = *(const bf16x8*)(
                cb + (w * 32 + nb * 16 + m) * 512 + ks * 32 + g * 8);

    // Staging geometry: instr i_ covers tile-row w*4+(i_>>1), half h=i_&1;
    // lane l takes chunk l of the 1KB half (fully linear global read).
    int cow[4];
#pragma unroll
    for (int q = 0; q < 4; ++q)
        cow[q] = (l & 56) + ((l & 7) ^ ((w * 4 + q) & 7));

    // LDS read bases (bytes): row m, chunk (ks*8 + (2g|2g+1)^(m&7)).
    const int rbo0 = m * 2048 + (((2 * g)     ^ (m & 7)) * 16);
    const int rbo1 = m * 2048 + (((2 * g + 1) ^ (m & 7)) * 16);

    // Output read-back geometry: 2 instructions of 8 rows x 8 chunks.
    const int orow_l = l >> 3;      // row within 8-row half
    const int opos = l & 7;         // 16B chunk position within 32-col piece

    f32x4 G[8];

#define SB __builtin_amdgcn_sched_barrier(0)
#define GLOAD(P)                                                          \
    { _Pragma("unroll")                                                   \
      for (int i_ = 0; i_ < 8; ++i_)                                      \
          G[i_] = *(const f32x4*)(x + (brow + (long)(P) * 16              \
                     + w * 4 + (i_ >> 1)) * 512 + (i_ & 1) * 256 + l * 4); }
#define DSWRITE()                                                         \
    { _Pragma("unroll")                                                   \
      for (int i_ = 0; i_ < 8; ++i_)                                      \
          *(f32x4*)(&lds[(w * 4 + (i_ >> 1)) * 512 + (i_ & 1) * 256       \
                         + cow[i_ >> 1] * 4]) = G[i_]; }

    // Prologue: tile 0 through registers into LDS.
    GLOAD(0);
    asm volatile("s_waitcnt vmcnt(0)" ::: "memory");
    DSWRITE();
    asm volatile("s_waitcnt lgkmcnt(0)" ::: "memory");
    __builtin_amdgcn_s_barrier();

#pragma unroll 1
    for (int p = 0; p < 16; ++p) {
        // P1: issue next tile's loads early (latency hides under compute).
        if (p < 15) { GLOAD(p + 1); }
        SB;

        // P2: compute pass p from LDS.
        f32x4 acc[2] = {f32x4{0.f, 0.f, 0.f, 0.f}, f32x4{0.f, 0.f, 0.f, 0.f}};
        float x2p = 0.f;
        const char* L = (const char*)&lds[0];
#pragma unroll
        for (int ks = 0; ks < 16; ++ks) {
            f32x4 u0 = *(const f32x4*)(L + rbo0 + ks * 128);
            f32x4 u1 = *(const f32x4*)(L + rbo1 + ks * 128);
            bf16x8 aF;
#pragma unroll
            for (int j = 0; j < 4; ++j) {
                aF[j]     = (__bf16)u0[j];
                aF[4 + j] = (__bf16)u1[j];
                x2p += u0[j] * u0[j] + u1[j] * u1[j];
            }
            acc[0] = __builtin_amdgcn_mfma_f32_16x16x32_bf16(aF, bR[0][ks], acc[0], 0, 0, 0);
            acc[1] = __builtin_amdgcn_mfma_f32_16x16x32_bf16(aF, bR[1][ks], acc[1], 0, 0, 0);
        }

        // P3: epilogue for these 16 rows.
        x2p += __shfl_xor(x2p, 16);
        x2p += __shfl_xor(x2p, 32);

        float x2r[4], rs[4];
#pragma unroll
        for (int r = 0; r < 4; ++r) {
            x2r[r] = __shfl(x2p, g * 4 + r);
            rs[r] = 0.f;
        }
#pragma unroll
        for (int nb = 0; nb < 2; ++nb)
#pragma unroll
            for (int r = 0; r < 4; ++r) {
                float d2 = fmaxf(x2r[r] + c2v[nb] - 2.f * acc[nb][r], 0.f);
                float qv = __builtin_amdgcn_rcpf(1.f + d2);  // ALPHA=1
                acc[nb][r] = qv;
                rs[r] += qv;
            }
#pragma unroll
        for (int r = 0; r < 4; ++r) {
            rs[r] += __shfl_xor(rs[r], 1);
            rs[r] += __shfl_xor(rs[r], 2);
            rs[r] += __shfl_xor(rs[r], 4);
            rs[r] += __shfl_xor(rs[r], 8);
        }
        if (m == 0) {
#pragma unroll
            for (int r = 0; r < 4; ++r) rsx[w][g * 4 + r] = rs[r];
        }
        asm volatile("s_waitcnt lgkmcnt(0)" ::: "memory");
        __builtin_amdgcn_s_barrier();      // BARRIER-A: rsx ready, tile reads done

        // Normalize -> wave-private qt (XOR-swizzled chunks) -> 2 full-line
        // nontemporal 1KB store instructions.
#pragma unroll
        for (int r = 0; r < 4; ++r) {
            const int row16 = g * 4 + r;
            const float inv = __builtin_amdgcn_rcpf(
                rsx[0][row16] + rsx[1][row16] + rsx[2][row16] + rsx[3][row16]);
#pragma unroll
            for (int nb = 0; nb < 2; ++nb) {
                const int chunk = nb * 4 + (m >> 2);
                qt[w][row16 * 32 + ((chunk ^ (row16 & 7)) * 4) + (m & 3)] =
                    acc[nb][r] * inv;
            }
        }
        // wave-private RAW on qt: compiler inserts the needed lgkmcnt.
        const long obase = brow + p * 16;
#pragma unroll
        for (int h = 0; h < 2; ++h) {
            const int row16 = h * 8 + orow_l;
            f32x4 v = *(const f32x4*)&qt[w][row16 * 32 +
                                            ((opos ^ (row16 & 7)) * 4)];
            __builtin_nontemporal_store(
                v, (f32x4*)(out + (obase + row16) * 128 + w * 32 + opos * 4));
        }
        SB;

        // P4: land next tile in LDS. vmcnt(2): keep the 2 newest (this pass's
        // stores), drain all 8 staged loads (in-order retirement).
        if (p < 15) {
            asm volatile("s_waitcnt vmcnt(2)" ::: "memory");
            SB;
            DSWRITE();
            asm volatile("s_waitcnt lgkmcnt(0)" ::: "memory");
            __builtin_amdgcn_s_barrier();  // BARRIER-B: tile p+1 visible to all
        }
    }
#undef GLOAD
#undef DSWRITE
#undef SB
}

extern "C" void kernel_launch(void* const* d_in, const int* in_sizes, int n_in,
                              void* d_out, int out_size, void* d_ws, size_t ws_size,
                              hipStream_t stream)
{
    const float* x = (const float*)d_in[0];
    const float* c = (const float*)d_in[1];
    float* out = (float*)d_out;

    float*  c2ws = (float*)d_ws;                        // 128 floats
    __bf16* cbws = (__bf16*)((char*)d_ws + 1024);       // 128x512 bf16 = 128 KB

    hipLaunchKernelGGL(prep_clusters, dim3(128), dim3(64), 0, stream, c, cbws, c2ws);

    const int N = in_sizes[0] / 512;                    // 131072 rows
    dim3 grid(N / 256), block(256);                     // 512 blocks = 2/CU
    hipLaunchKernelGGL(cluster_q_mfma, grid, block, 0, stream, x, cbws, c2ws, out);
}